// Round 6
// baseline (4344.336 us; speedup 1.0000x reference)
//
#include <hip/hip_runtime.h>
#include <math.h>

#define B 4
#define N 32768
#define D 131
#define S 1024
#define RAD2 0.1f      // reference compares d2 <= RADIUS (=0.1) on SQUARED distance
#define G 8            // FPS blocks per batch
#define TPB 512        // FPS threads per block
#define PPT 8          // N/G/TPB points per thread
#define WAVES_PER_BATCH 64   // G * (TPB/64) sync participants = 64 slots

// ---------------------------------------------------------------------------
// Copy x (4x32768x131 f32 = 64MB) straight to out. float4 grid-stride.
// ---------------------------------------------------------------------------
__global__ void copy_x_kernel(const float* __restrict__ x, float* __restrict__ out) {
    const size_t total4 = (size_t)B * N * D / 4;
    const float4* __restrict__ src = (const float4*)x;
    float4* __restrict__ dst = (float4*)out;
    for (size_t i = (size_t)blockIdx.x * blockDim.x + threadIdx.x; i < total4;
         i += (size_t)gridDim.x * blockDim.x)
        dst[i] = src[i];
}

// ---------------------------------------------------------------------------
// Pack pts = x[:,:,:3] into SoA (px|py|pz) AND packed float4 {x,y,z,0} for the
// per-step centroid gather (one dwordx4 round-trip).
// ---------------------------------------------------------------------------
__global__ void pack_kernel(const float* __restrict__ x, float* __restrict__ ws) {
    int i = blockIdx.x * blockDim.x + threadIdx.x;
    if (i < B * N) {
        const float* __restrict__ s = x + (size_t)i * D;
        float a = s[0], bb = s[1], c = s[2];
        ws[i]             = a;
        ws[B * N + i]     = bb;
        ws[2 * B * N + i] = c;
        float4* w4 = (float4*)(ws + (size_t)3 * B * N);
        w4[i] = make_float4(a, bb, c, 0.0f);
    }
}

// ---------------------------------------------------------------------------
// Barrier-free multi-wave FPS. G=8 blocks/batch x 512 thr x 8 pts/thread.
// Every WAVE is a sync participant: 64 waves per batch, 64 u64 slots.
//   key = [f32 bits of best : 32][ (32767-idx) : 15 ][ 0:6 ][ tag=s+1 : 11 ]
// Per step: compute -> intra-wave butterfly -> lane0 stores wave key ->
// every wave polls all 64 slots (1 u64/lane, coalesced) until tags fresh ->
// 6-stage u64 butterfly -> sel -> uniform p4[sel] gather. NO __syncthreads,
// NO LDS in the loop. Double-buffer safety: a wave stores tag s+3 into a
// buffer only after its step-(s+1) poll succeeded, which needs every wave to
// have stored s+2, which (program order) means every wave finished reading
// step s. Coordinates pinned in VGPRs via empty asm (compiler otherwise
// rematerializes them as per-step L1 reloads - seen in round 5, VGPR=32).
// ---------------------------------------------------------------------------
__launch_bounds__(TPB)
__global__ void fps_kernel(const float* __restrict__ ws,
                           unsigned long long* __restrict__ gslot,  // [B][2][64], zeroed
                           float* __restrict__ out_idx,
                           int* __restrict__ idx_int) {
    const int b = blockIdx.x / G;
    const int g = blockIdx.x % G;
    const int t = threadIdx.x;
    const int lane = t & 63;
    const int wave = (g * TPB + t) >> 6;          // 0..63 within this batch

    const float* __restrict__ px = ws + (size_t)b * N;
    const float* __restrict__ py = ws + (size_t)(B + b) * N;
    const float* __restrict__ pz = ws + (size_t)(2 * B + b) * N;
    const float4* __restrict__ p4 = (const float4*)(ws + (size_t)3 * B * N) + (size_t)b * N;
    unsigned long long* __restrict__ slots = gslot + (size_t)b * 2 * WAVES_PER_BATCH;

    // Thread owns points p = base + 2*t + 1024*i + {0,1}, i=0..3 (ascending p).
    const int base = g * (N / G);
    float lx[PPT], ly[PPT], lz[PPT], lcl[PPT];
    #pragma unroll
    for (int i = 0; i < PPT / 2; ++i) {
        int p = base + 2 * t + 2 * TPB * i;
        float2 vx = *(const float2*)&px[p];
        float2 vy = *(const float2*)&py[p];
        float2 vz = *(const float2*)&pz[p];
        lx[2*i] = vx.x; lx[2*i+1] = vx.y;
        ly[2*i] = vy.x; ly[2*i+1] = vy.y;
        lz[2*i] = vz.x; lz[2*i+1] = vz.y;
        lcl[2*i] = INFINITY; lcl[2*i+1] = INFINITY;
        // Pin in VGPRs: opaque to the compiler, prevents reload-sinking.
        asm volatile("" : "+v"(lx[2*i]), "+v"(lx[2*i+1]),
                          "+v"(ly[2*i]), "+v"(ly[2*i+1]),
                          "+v"(lz[2*i]), "+v"(lz[2*i+1]));
    }

    float4 c4 = p4[0];   // centroid 0 (reference starts at sel=0)

    for (int s = 0; s < S; ++s) {
        const float cx = c4.x, cy = c4.y, cz = c4.z;

        float best = -INFINITY;
        int   bidx = 0;
        #pragma unroll
        for (int i = 0; i < PPT / 2; ++i) {
            const int p = base + 2 * t + 2 * TPB * i;
            {
                float dx = __fsub_rn(cx, lx[2*i]);
                float dy = __fsub_rn(cy, ly[2*i]);
                float dz = __fsub_rn(cz, lz[2*i]);
                float d2 = __fadd_rn(__fadd_rn(__fmul_rn(dx, dx), __fmul_rn(dy, dy)),
                                     __fmul_rn(dz, dz));
                float c = fminf(lcl[2*i], d2);
                lcl[2*i] = c;
                if (c > best) { best = c; bidx = p; }     // strict >: smallest p wins
            }
            {
                float dx = __fsub_rn(cx, lx[2*i+1]);
                float dy = __fsub_rn(cy, ly[2*i+1]);
                float dz = __fsub_rn(cz, lz[2*i+1]);
                float d2 = __fadd_rn(__fadd_rn(__fmul_rn(dx, dx), __fmul_rn(dy, dy)),
                                     __fmul_rn(dz, dz));
                float c = fminf(lcl[2*i+1], d2);
                lcl[2*i+1] = c;
                if (c > best) { best = c; bidx = p + 1; }
            }
        }

        // intra-wave butterfly argmax on (value, smallest idx)
        unsigned hi = __float_as_uint(best);          // best >= 0 => bits monotone
        unsigned lo2 = (unsigned)(32767 - bidx);      // bigger == smaller idx

        #define FPS_COMBINE(OHI, OLO) \
            { unsigned _oh = (OHI), _ol = (OLO); \
              if (_oh > hi || (_oh == hi && _ol > lo2)) { hi = _oh; lo2 = _ol; } }
        { unsigned a = (unsigned)__builtin_amdgcn_update_dpp(0, (int)hi, 0xB1, 0xf, 0xf, true);
          unsigned c2 = (unsigned)__builtin_amdgcn_update_dpp(0, (int)lo2, 0xB1, 0xf, 0xf, true);
          FPS_COMBINE(a, c2); }
        { unsigned a = (unsigned)__builtin_amdgcn_update_dpp(0, (int)hi, 0x4E, 0xf, 0xf, true);
          unsigned c2 = (unsigned)__builtin_amdgcn_update_dpp(0, (int)lo2, 0x4E, 0xf, 0xf, true);
          FPS_COMBINE(a, c2); }
        { unsigned a = (unsigned)__builtin_amdgcn_update_dpp(0, (int)hi, 0x141, 0xf, 0xf, true);
          unsigned c2 = (unsigned)__builtin_amdgcn_update_dpp(0, (int)lo2, 0x141, 0xf, 0xf, true);
          FPS_COMBINE(a, c2); }
        { unsigned a = (unsigned)__builtin_amdgcn_update_dpp(0, (int)hi, 0x140, 0xf, 0xf, true);
          unsigned c2 = (unsigned)__builtin_amdgcn_update_dpp(0, (int)lo2, 0x140, 0xf, 0xf, true);
          FPS_COMBINE(a, c2); }
        { unsigned a = (unsigned)__builtin_amdgcn_ds_swizzle((int)hi, 0x401F);
          unsigned c2 = (unsigned)__builtin_amdgcn_ds_swizzle((int)lo2, 0x401F);
          FPS_COMBINE(a, c2); }
        { unsigned a = (unsigned)__shfl_xor((int)hi, 32, 64);
          unsigned c2 = (unsigned)__shfl_xor((int)lo2, 32, 64);
          FPS_COMBINE(a, c2); }
        #undef FPS_COMBINE

        const int buf = s & 1;
        const unsigned tag = (unsigned)(s + 1);      // 1..1024, 11 bits, never 0
        if (lane == 0) {
            unsigned long long k = ((unsigned long long)hi << 32) |
                                   ((unsigned long long)lo2 << 17) | tag;
            __hip_atomic_store(&slots[buf * WAVES_PER_BATCH + wave], k,
                               __ATOMIC_RELAXED, __HIP_MEMORY_SCOPE_AGENT);
        }

        // Every wave polls all 64 slots: lane i watches slot i.
        unsigned long long kk;
        unsigned long long* myslot = &slots[buf * WAVES_PER_BATCH + lane];
        do {
            kk = __hip_atomic_load(myslot, __ATOMIC_RELAXED, __HIP_MEMORY_SCOPE_AGENT);
        } while (__any((unsigned)(kk & 0x7FFull) != tag));

        // 64-lane butterfly max -> winner key in every lane
        #pragma unroll
        for (int off = 1; off < 64; off <<= 1) {
            unsigned long long o = (unsigned long long)__shfl_xor((long long)kk, off, 64);
            if (o > kk) kk = o;
        }
        int sel = 32767 - (int)((kk >> 17) & 0x7FFF);
        sel = __builtin_amdgcn_readfirstlane(sel);   // wave-uniform -> scalar path

        if (g == 0 && t == 0) {
            out_idx[b * S + s] = (float)sel;
            idx_int[b * S + s] = sel;
        }
        c4 = p4[sel];      // uniform gather of next centroid
    }
}

// ---------------------------------------------------------------------------
// Ball query counts: one block (256 thr) per (batch, centroid).
// ---------------------------------------------------------------------------
__launch_bounds__(256)
__global__ void ballq_kernel(const float* __restrict__ ws,
                             const int* __restrict__ idx_int,
                             float* __restrict__ out_counts) {
    __shared__ int s_part[4];
    const int b = blockIdx.x >> 10;
    const int j = blockIdx.x & 1023;
    const int t = threadIdx.x;
    const float* __restrict__ px = ws + (size_t)b * N;
    const float* __restrict__ py = ws + (size_t)(B + b) * N;
    const float* __restrict__ pz = ws + (size_t)(2 * B + b) * N;

    const int ci = idx_int[b * S + j];
    const float cx = px[ci], cy = py[ci], cz = pz[ci];

    int cnt = 0;
    #pragma unroll 4
    for (int p = t; p < N; p += 256) {
        float dx = __fsub_rn(cx, px[p]);
        float dy = __fsub_rn(cy, py[p]);
        float dz = __fsub_rn(cz, pz[p]);
        float d2 = __fadd_rn(__fadd_rn(__fmul_rn(dx, dx), __fmul_rn(dy, dy)),
                             __fmul_rn(dz, dz));
        cnt += (d2 <= RAD2) ? 1 : 0;
    }
    #pragma unroll
    for (int off = 1; off < 64; off <<= 1)
        cnt += __shfl_xor(cnt, off, 64);
    if ((t & 63) == 0) s_part[t >> 6] = cnt;
    __syncthreads();
    if (t == 0)
        out_counts[b * S + j] = (float)(s_part[0] + s_part[1] + s_part[2] + s_part[3]);
}

// ---------------------------------------------------------------------------
extern "C" void kernel_launch(void* const* d_in, const int* in_sizes, int n_in,
                              void* d_out, int out_size, void* d_ws, size_t ws_size,
                              hipStream_t stream) {
    const float* x = (const float*)d_in[0];
    float* out = (float*)d_out;
    float* ws = (float*)d_ws;   // layout: px|py|pz (3BN) | float4 pack (4BN) | idx ints | slots
    int* idx_int = (int*)(ws + (size_t)7 * B * N);
    unsigned long long* gslot = (unsigned long long*)(idx_int + B * S);  // 16B-aligned

    float* out_x      = out;                         // B*N*D floats
    float* out_idx    = out + (size_t)B * N * D;     // B*S floats (idx as f32)
    float* out_counts = out_idx + (size_t)B * S;     // B*S floats (counts as f32)

    // zero the B*2*64 u64 sync slots every launch (deterministic, capturable)
    hipMemsetAsync(gslot, 0, (size_t)B * 2 * WAVES_PER_BATCH * sizeof(unsigned long long),
                   stream);

    hipLaunchKernelGGL(pack_kernel, dim3((B * N + 255) / 256), dim3(256), 0, stream, x, ws);
    hipLaunchKernelGGL(copy_x_kernel, dim3(2048), dim3(256), 0, stream, x, out_x);
    hipLaunchKernelGGL(fps_kernel, dim3(B * G), dim3(TPB), 0, stream, ws, gslot, out_idx, idx_int);
    hipLaunchKernelGGL(ballq_kernel, dim3(B * S), dim3(256), 0, stream, ws, idx_int, out_counts);
}

// Round 7
// 2915.271 us; speedup vs baseline: 1.4902x; 1.4902x over previous
//
#include <hip/hip_runtime.h>
#include <math.h>

#define B 4
#define N 32768
#define D 131
#define S 1024
#define RAD2 0.1f      // reference compares d2 <= RADIUS (=0.1) on SQUARED distance
#define GPB 32         // participant blocks per batch
#define TPB 512        // threads per fps block
#define SLICE (N / GPB)   // 1024 points per batch per block -> 2 pts/thread

// ---------------------------------------------------------------------------
// Copy x (4x32768x131 f32 = 64MB) straight to out. float4 grid-stride.
// ---------------------------------------------------------------------------
__global__ void copy_x_kernel(const float* __restrict__ x, float* __restrict__ out) {
    const size_t total4 = (size_t)B * N * D / 4;
    const float4* __restrict__ src = (const float4*)x;
    float4* __restrict__ dst = (float4*)out;
    for (size_t i = (size_t)blockIdx.x * blockDim.x + threadIdx.x; i < total4;
         i += (size_t)gridDim.x * blockDim.x)
        dst[i] = src[i];
}

// ---------------------------------------------------------------------------
// Pack pts = x[:,:,:3] into SoA (px|py|pz) AND packed float4 {x,y,z,0}.
// ---------------------------------------------------------------------------
__global__ void pack_kernel(const float* __restrict__ x, float* __restrict__ ws) {
    int i = blockIdx.x * blockDim.x + threadIdx.x;
    if (i < B * N) {
        const float* __restrict__ s = x + (size_t)i * D;
        float a = s[0], bb = s[1], c = s[2];
        ws[i]             = a;
        ws[B * N + i]     = bb;
        ws[2 * B * N + i] = c;
        float4* w4 = (float4*)(ws + (size_t)3 * B * N);
        w4[i] = make_float4(a, bb, c, 0.0f);
    }
}

// ---------------------------------------------------------------------------
// Dual-chain pipelined FPS.
// 64 blocks x 512 thr. Block (pair,g): pair = bid/32 handles batches
// {2*pair, 2*pair+1}; g = bid%32 owns points [g*1024, (g+1)*1024) of each.
// Segment(c,s): compute chain c step s -> wave butterfly -> [issue poll]
// -> LDS block-reduce (1 barrier) -> store block key -> consume poll for the
// OTHER chain's previous step (stored 1 full segment ago -> ~1 poll iter)
// -> 5-stage shuffle reduce over 32 slots -> sel -> centroid gather.
// The cross-XCD store->visibility latency of chain c hides under chain c'!=c's
// compute. Keys self-tagged: [f32 val:32][32767-idx:15][0:6][tag=s+1:11];
// u64 max == (max value, then min index); tag freshness-checks the slot.
// ---------------------------------------------------------------------------
__launch_bounds__(TPB)
__global__ void fps_kernel(const float* __restrict__ ws,
                           unsigned long long* __restrict__ gslot,  // [2][2][2][GPB] zeroed
                           float* __restrict__ out_idx,
                           int* __restrict__ idx_int) {
    const int pair = blockIdx.x / GPB;     // 0: batches 0,1  1: batches 2,3
    const int g    = blockIdx.x % GPB;
    const int t    = threadIdx.x;
    const int lane = t & 63;
    const int w    = t >> 6;               // wave 0..7

    __shared__ unsigned long long s_wk[2][8];   // per-chain wave keys

    const int batch0 = 2 * pair;
    const float* px[2]; const float* py[2]; const float* pz[2]; const float4* p4[2];
    #pragma unroll
    for (int c = 0; c < 2; ++c) {
        const int b = batch0 + c;
        px[c] = ws + (size_t)b * N;
        py[c] = ws + (size_t)(B + b) * N;
        pz[c] = ws + (size_t)(2 * B + b) * N;
        p4[c] = (const float4*)(ws + (size_t)3 * B * N) + (size_t)b * N;
    }
    unsigned long long* __restrict__ slots = gslot + (size_t)pair * (2 * 2 * GPB);
    // slots flat layout: [(chain*2 + buf) * GPB + slot]

    const int p0 = g * SLICE + 2 * t;      // this thread's 2 points: p0, p0+1

    float lx[2][2], ly[2][2], lz[2][2], lcl[2][2];
    float4 cc4[2];
    #pragma unroll
    for (int c = 0; c < 2; ++c) {
        float2 vx = *(const float2*)&px[c][p0];
        float2 vy = *(const float2*)&py[c][p0];
        float2 vz = *(const float2*)&pz[c][p0];
        lx[c][0] = vx.x; lx[c][1] = vx.y;
        ly[c][0] = vy.x; ly[c][1] = vy.y;
        lz[c][0] = vz.x; lz[c][1] = vz.y;
        lcl[c][0] = INFINITY; lcl[c][1] = INFINITY;
        cc4[c] = p4[c][0];                 // centroid 0 (reference starts at sel=0)
    }

    // 6-stage intra-wave butterfly argmax on (value, smallest idx)
    #define WAVE_BFLY()                                                              \
        {                                                                            \
          _Pragma("unroll") for (int st = 0; st < 6; ++st) {                         \
            unsigned a, c2;                                                          \
            if (st == 0) { a = (unsigned)__builtin_amdgcn_update_dpp(0,(int)hi,0xB1,0xf,0xf,true);  \
                           c2= (unsigned)__builtin_amdgcn_update_dpp(0,(int)lo2,0xB1,0xf,0xf,true);}\
            else if (st==1){a = (unsigned)__builtin_amdgcn_update_dpp(0,(int)hi,0x4E,0xf,0xf,true); \
                           c2= (unsigned)__builtin_amdgcn_update_dpp(0,(int)lo2,0x4E,0xf,0xf,true);}\
            else if (st==2){a = (unsigned)__builtin_amdgcn_update_dpp(0,(int)hi,0x141,0xf,0xf,true);\
                           c2= (unsigned)__builtin_amdgcn_update_dpp(0,(int)lo2,0x141,0xf,0xf,true);}\
            else if (st==3){a = (unsigned)__builtin_amdgcn_update_dpp(0,(int)hi,0x140,0xf,0xf,true);\
                           c2= (unsigned)__builtin_amdgcn_update_dpp(0,(int)lo2,0x140,0xf,0xf,true);}\
            else if (st==4){a = (unsigned)__builtin_amdgcn_ds_swizzle((int)hi,0x401F);              \
                           c2= (unsigned)__builtin_amdgcn_ds_swizzle((int)lo2,0x401F);}             \
            else          {a = (unsigned)__shfl_xor((int)hi,32,64);                                 \
                           c2= (unsigned)__shfl_xor((int)lo2,32,64);}                               \
            if (a > hi || (a == hi && c2 > lo2)) { hi = a; lo2 = c2; }              \
          }                                                                          \
        }

    #define SEG(c, sstep, expt)                                                      \
    {                                                                                \
        enum { CC = 1 - (c) };                                                       \
        const unsigned exp_tag = (unsigned)(expt);                                   \
        /* 1. compute chain c, step sstep */                                         \
        const float cx = cc4[c].x, cy = cc4[c].y, cz = cc4[c].z;                     \
        float d2a, d2b;                                                              \
        { float dx=__fsub_rn(cx,lx[c][0]), dy=__fsub_rn(cy,ly[c][0]), dz=__fsub_rn(cz,lz[c][0]); \
          d2a=__fadd_rn(__fadd_rn(__fmul_rn(dx,dx),__fmul_rn(dy,dy)),__fmul_rn(dz,dz)); }        \
        { float dx=__fsub_rn(cx,lx[c][1]), dy=__fsub_rn(cy,ly[c][1]), dz=__fsub_rn(cz,lz[c][1]); \
          d2b=__fadd_rn(__fadd_rn(__fmul_rn(dx,dx),__fmul_rn(dy,dy)),__fmul_rn(dz,dz)); }        \
        float v0 = fminf(lcl[c][0], d2a); lcl[c][0] = v0;                            \
        float v1 = fminf(lcl[c][1], d2b); lcl[c][1] = v1;                            \
        float best; int bidx;                                                        \
        if (v1 > v0) { best = v1; bidx = p0 + 1; } else { best = v0; bidx = p0; }    \
        unsigned hi  = __float_as_uint(best);                                        \
        unsigned lo2 = (unsigned)(32767 - bidx);                                     \
        WAVE_BFLY();                                                                 \
        /* 2. early poll issue (latency hidden under barrier + reduce) */            \
        unsigned long long kk = 0; unsigned long long* ms = 0;                       \
        if (exp_tag) {                                                               \
            ms = &slots[((int)CC * 2 + (int)((exp_tag - 1) & 1u)) * GPB + (lane & 31)]; \
            kk = __hip_atomic_load(ms, __ATOMIC_RELAXED, __HIP_MEMORY_SCOPE_AGENT);  \
        }                                                                            \
        /* 3. block reduce via LDS (the only barrier in the segment) */              \
        const unsigned long long mykey = ((unsigned long long)hi << 32) |            \
            ((unsigned long long)lo2 << 17) | (unsigned)((sstep) + 1);               \
        if (lane == 0) s_wk[(c)][w] = mykey;                                         \
        __syncthreads();                                                             \
        unsigned long long bk = s_wk[(c)][0];                                        \
        _Pragma("unroll") for (int j = 1; j < 8; ++j)                                \
            { unsigned long long v = s_wk[(c)][j]; if (v > bk) bk = v; }             \
        /* 4. publish block key */                                                   \
        if (t == 0)                                                                  \
            __hip_atomic_store(&slots[((c) * 2 + ((sstep) & 1)) * GPB + g], bk,      \
                               __ATOMIC_RELAXED, __HIP_MEMORY_SCOPE_AGENT);          \
        /* 5. consume other chain's previous step */                                 \
        if (exp_tag) {                                                               \
            while (__any((unsigned)(kk & 0x7FFull) != exp_tag))                      \
                kk = __hip_atomic_load(ms, __ATOMIC_RELAXED, __HIP_MEMORY_SCOPE_AGENT); \
            _Pragma("unroll") for (int off = 1; off < 32; off <<= 1) {               \
                unsigned long long o = (unsigned long long)__shfl_xor((long long)kk, off, 64); \
                if (o > kk) kk = o;                                                  \
            }                                                                        \
            int sl = 32767 - (int)((kk >> 17) & 0x7FFF);                             \
            sl = __builtin_amdgcn_readfirstlane(sl);                                 \
            cc4[CC] = p4[CC][sl];                                                    \
            if (g == 0 && t == 0) {                                                  \
                out_idx[(size_t)(batch0 + (int)CC) * S + (exp_tag - 1)] = (float)sl; \
                idx_int[(batch0 + (int)CC) * S + (exp_tag - 1)] = sl;                \
            }                                                                        \
        }                                                                            \
    }

    for (int s = 0; s < S; ++s) {
        SEG(0, s, s);        // consumes chain 1's step s-1 (tag s); skipped at s=0
        SEG(1, s, s + 1);    // consumes chain 0's step s   (tag s+1)
    }

    // epilogue: chain 1's final step (tag S)
    if (g == 0) {
        unsigned long long* ms = &slots[(1 * 2 + ((S - 1) & 1)) * GPB + (lane & 31)];
        unsigned long long kk = __hip_atomic_load(ms, __ATOMIC_RELAXED, __HIP_MEMORY_SCOPE_AGENT);
        while (__any((unsigned)(kk & 0x7FFull) != (unsigned)S))
            kk = __hip_atomic_load(ms, __ATOMIC_RELAXED, __HIP_MEMORY_SCOPE_AGENT);
        #pragma unroll
        for (int off = 1; off < 32; off <<= 1) {
            unsigned long long o = (unsigned long long)__shfl_xor((long long)kk, off, 64);
            if (o > kk) kk = o;
        }
        if (t == 0) {
            int sl = 32767 - (int)((kk >> 17) & 0x7FFF);
            out_idx[(size_t)(batch0 + 1) * S + (S - 1)] = (float)sl;
            idx_int[(batch0 + 1) * S + (S - 1)] = sl;
        }
    }
    #undef SEG
    #undef WAVE_BFLY
}

// ---------------------------------------------------------------------------
// Ball query counts: one block (256 thr) per (batch, centroid).
// ---------------------------------------------------------------------------
__launch_bounds__(256)
__global__ void ballq_kernel(const float* __restrict__ ws,
                             const int* __restrict__ idx_int,
                             float* __restrict__ out_counts) {
    __shared__ int s_part[4];
    const int b = blockIdx.x >> 10;
    const int j = blockIdx.x & 1023;
    const int t = threadIdx.x;
    const float* __restrict__ px = ws + (size_t)b * N;
    const float* __restrict__ py = ws + (size_t)(B + b) * N;
    const float* __restrict__ pz = ws + (size_t)(2 * B + b) * N;

    const int ci = idx_int[b * S + j];
    const float cx = px[ci], cy = py[ci], cz = pz[ci];

    int cnt = 0;
    #pragma unroll 4
    for (int p = t; p < N; p += 256) {
        float dx = __fsub_rn(cx, px[p]);
        float dy = __fsub_rn(cy, py[p]);
        float dz = __fsub_rn(cz, pz[p]);
        float d2 = __fadd_rn(__fadd_rn(__fmul_rn(dx, dx), __fmul_rn(dy, dy)),
                             __fmul_rn(dz, dz));
        cnt += (d2 <= RAD2) ? 1 : 0;
    }
    #pragma unroll
    for (int off = 1; off < 64; off <<= 1)
        cnt += __shfl_xor(cnt, off, 64);
    if ((t & 63) == 0) s_part[t >> 6] = cnt;
    __syncthreads();
    if (t == 0)
        out_counts[b * S + j] = (float)(s_part[0] + s_part[1] + s_part[2] + s_part[3]);
}

// ---------------------------------------------------------------------------
extern "C" void kernel_launch(void* const* d_in, const int* in_sizes, int n_in,
                              void* d_out, int out_size, void* d_ws, size_t ws_size,
                              hipStream_t stream) {
    const float* x = (const float*)d_in[0];
    float* out = (float*)d_out;
    float* ws = (float*)d_ws;   // px|py|pz (3BN) | float4 pack (4BN) | idx ints | slots
    int* idx_int = (int*)(ws + (size_t)7 * B * N);
    unsigned long long* gslot = (unsigned long long*)(idx_int + B * S);  // 8B-aligned

    float* out_x      = out;                         // B*N*D floats
    float* out_idx    = out + (size_t)B * N * D;     // B*S floats (idx as f32)
    float* out_counts = out_idx + (size_t)B * S;     // B*S floats (counts as f32)

    // zero the 2*2*2*GPB u64 sync slots every launch (deterministic, capturable)
    hipMemsetAsync(gslot, 0, (size_t)2 * 2 * 2 * GPB * sizeof(unsigned long long), stream);

    hipLaunchKernelGGL(pack_kernel, dim3((B * N + 255) / 256), dim3(256), 0, stream, x, ws);
    hipLaunchKernelGGL(copy_x_kernel, dim3(2048), dim3(256), 0, stream, x, out_x);
    hipLaunchKernelGGL(fps_kernel, dim3(2 * GPB), dim3(TPB), 0, stream, ws, gslot, out_idx, idx_int);
    hipLaunchKernelGGL(ballq_kernel, dim3(B * S), dim3(256), 0, stream, ws, idx_int, out_counts);
}

// Round 8
// 2353.033 us; speedup vs baseline: 1.8463x; 1.2389x over previous
//
#include <hip/hip_runtime.h>
#include <math.h>

#define B 4
#define N 32768
#define D 131
#define S 1024
#define RAD2 0.1f      // reference compares d2 <= RADIUS (=0.1) on SQUARED distance
#define G 16           // FPS blocks per batch
#define TPB 256        // threads per fps/copy block
#define PPT 8          // points per thread
#define NFPS (B * G)   // 64 fps blocks
#define COPY_BLOCKS 192

// ---------------------------------------------------------------------------
// Pack pts = x[:,:,:3] into SoA (px|py|pz) AND packed float4 {x,y,z,0} for the
// per-step centroid gather (one dwordx4 round-trip).
// ---------------------------------------------------------------------------
__global__ void pack_kernel(const float* __restrict__ x, float* __restrict__ ws) {
    int i = blockIdx.x * blockDim.x + threadIdx.x;
    if (i < B * N) {
        const float* __restrict__ s = x + (size_t)i * D;
        float a = s[0], bb = s[1], c = s[2];
        ws[i]             = a;
        ws[B * N + i]     = bb;
        ws[2 * B * N + i] = c;
        float4* w4 = (float4*)(ws + (size_t)3 * B * N);
        w4[i] = make_float4(a, bb, c, 0.0f);
    }
}

// ---------------------------------------------------------------------------
// Fused FPS + copy kernel, 256 blocks x 256 thr.
//  - blocks [0,64):  FPS, 16 blocks per batch, one chain per batch (4 chains
//    fully parallel). Per step: compute 8 pts -> wave butterfly -> LDS block
//    reduce (the ONLY barrier) -> block key store (agent scope, relaxed,
//    self-tagged) -> ALL waves poll the 16 block slots (1 coalesced load) ->
//    4-stage in-register u64 reduce -> sel -> uniform p4[sel] gather.
//  - blocks [64,256): grid-stride float4 copy of x (64 MB) to out; overlaps
//    with the latency-bound FPS chains (fps uses ~0 HBM bandwidth).
// Key: [f32 val:32][32767-idx:15][0:6][tag=s+1:11]. Equal tags within a step
// => u64 max == (max value, then min index) == exact ref tie-break.
// Double-buffer safety: slot for step s (buf s&1) is overwritten first at
// step s+2, and the writer's step-(s+1) poll succeeding implies every block
// passed its step-(s+1) barrier, which implies all its waves consumed step s.
// ---------------------------------------------------------------------------
__launch_bounds__(TPB)
__global__ void fps_copy_kernel(const float* __restrict__ x,
                                const float* __restrict__ ws,
                                unsigned long long* __restrict__ gslot, // [B][2][G] zeroed
                                float* __restrict__ out_idx,
                                int* __restrict__ idx_int,
                                float* __restrict__ out_x) {
    if (blockIdx.x >= NFPS) {
        // ---- copy branch: 192 blocks stream x -> out_x ----
        const size_t total4 = (size_t)B * N * D / 4;
        const float4* __restrict__ src = (const float4*)x;
        float4* __restrict__ dst = (float4*)out_x;
        for (size_t i = (size_t)(blockIdx.x - NFPS) * TPB + threadIdx.x; i < total4;
             i += (size_t)COPY_BLOCKS * TPB)
            dst[i] = src[i];
        return;
    }

    // ---- FPS branch ----
    const int b = blockIdx.x >> 4;          // batch  (bid / G)
    const int g = blockIdx.x & 15;          // participant id within batch
    const int t = threadIdx.x;
    const int lane = t & 63;
    const int w = t >> 6;                   // wave 0..3

    __shared__ unsigned long long s_wk[2][4];   // double-buffered wave keys

    const float* __restrict__ px = ws + (size_t)b * N;
    const float* __restrict__ py = ws + (size_t)(B + b) * N;
    const float* __restrict__ pz = ws + (size_t)(2 * B + b) * N;
    const float4* __restrict__ p4 = (const float4*)(ws + (size_t)3 * B * N) + (size_t)b * N;
    unsigned long long* __restrict__ slots = gslot + (size_t)b * 2 * G;

    // Thread owns points p = base + 2*t + 512*i + {0,1}, i=0..3 (ascending p).
    const int base = g * (N / G);
    float lx[PPT], ly[PPT], lz[PPT], lcl[PPT];
    #pragma unroll
    for (int i = 0; i < PPT / 2; ++i) {
        int p = base + 2 * t + 2 * TPB * i;
        float2 vx = *(const float2*)&px[p];
        float2 vy = *(const float2*)&py[p];
        float2 vz = *(const float2*)&pz[p];
        lx[2*i] = vx.x; lx[2*i+1] = vx.y;
        ly[2*i] = vy.x; ly[2*i+1] = vy.y;
        lz[2*i] = vz.x; lz[2*i+1] = vz.y;
        lcl[2*i] = INFINITY; lcl[2*i+1] = INFINITY;
    }

    float4 c4 = p4[0];   // centroid 0 (reference starts at sel=0)

    for (int s = 0; s < S; ++s) {
        const float cx = c4.x, cy = c4.y, cz = c4.z;

        float best = -INFINITY;
        int   bidx = 0;
        #pragma unroll
        for (int i = 0; i < PPT / 2; ++i) {
            const int p = base + 2 * t + 2 * TPB * i;
            {
                float dx = __fsub_rn(cx, lx[2*i]);
                float dy = __fsub_rn(cy, ly[2*i]);
                float dz = __fsub_rn(cz, lz[2*i]);
                float d2 = __fadd_rn(__fadd_rn(__fmul_rn(dx, dx), __fmul_rn(dy, dy)),
                                     __fmul_rn(dz, dz));
                float c = fminf(lcl[2*i], d2);
                lcl[2*i] = c;
                if (c > best) { best = c; bidx = p; }     // strict >: smallest p wins
            }
            {
                float dx = __fsub_rn(cx, lx[2*i+1]);
                float dy = __fsub_rn(cy, ly[2*i+1]);
                float dz = __fsub_rn(cz, lz[2*i+1]);
                float d2 = __fadd_rn(__fadd_rn(__fmul_rn(dx, dx), __fmul_rn(dy, dy)),
                                     __fmul_rn(dz, dz));
                float c = fminf(lcl[2*i+1], d2);
                lcl[2*i+1] = c;
                if (c > best) { best = c; bidx = p + 1; }
            }
        }

        // intra-wave butterfly argmax on (value, smallest idx)
        unsigned hi  = __float_as_uint(best);         // best >= 0 => bits monotone
        unsigned lo2 = (unsigned)(32767 - bidx);      // bigger == smaller idx

        #define FPS_COMBINE(OHI, OLO) \
            { unsigned _oh = (OHI), _ol = (OLO); \
              if (_oh > hi || (_oh == hi && _ol > lo2)) { hi = _oh; lo2 = _ol; } }
        { unsigned a = (unsigned)__builtin_amdgcn_update_dpp(0, (int)hi, 0xB1, 0xf, 0xf, true);
          unsigned c2 = (unsigned)__builtin_amdgcn_update_dpp(0, (int)lo2, 0xB1, 0xf, 0xf, true);
          FPS_COMBINE(a, c2); }
        { unsigned a = (unsigned)__builtin_amdgcn_update_dpp(0, (int)hi, 0x4E, 0xf, 0xf, true);
          unsigned c2 = (unsigned)__builtin_amdgcn_update_dpp(0, (int)lo2, 0x4E, 0xf, 0xf, true);
          FPS_COMBINE(a, c2); }
        { unsigned a = (unsigned)__builtin_amdgcn_update_dpp(0, (int)hi, 0x141, 0xf, 0xf, true);
          unsigned c2 = (unsigned)__builtin_amdgcn_update_dpp(0, (int)lo2, 0x141, 0xf, 0xf, true);
          FPS_COMBINE(a, c2); }
        { unsigned a = (unsigned)__builtin_amdgcn_update_dpp(0, (int)hi, 0x140, 0xf, 0xf, true);
          unsigned c2 = (unsigned)__builtin_amdgcn_update_dpp(0, (int)lo2, 0x140, 0xf, 0xf, true);
          FPS_COMBINE(a, c2); }
        { unsigned a = (unsigned)__builtin_amdgcn_ds_swizzle((int)hi, 0x401F);
          unsigned c2 = (unsigned)__builtin_amdgcn_ds_swizzle((int)lo2, 0x401F);
          FPS_COMBINE(a, c2); }
        { unsigned a = (unsigned)__shfl_xor((int)hi, 32, 64);
          unsigned c2 = (unsigned)__shfl_xor((int)lo2, 32, 64);
          FPS_COMBINE(a, c2); }
        #undef FPS_COMBINE

        const int buf = s & 1;
        const unsigned tag = (unsigned)(s + 1);      // 1..1024, 11 bits, never 0
        const unsigned long long mykey = ((unsigned long long)hi << 32) |
                                         ((unsigned long long)lo2 << 17) | tag;
        if (lane == 0) s_wk[buf][w] = mykey;
        __syncthreads();                             // the ONLY barrier per step

        // block key = max of 4 wave keys (broadcast LDS reads, all threads)
        unsigned long long bk = s_wk[buf][0];
        #pragma unroll
        for (int j = 1; j < 4; ++j) { unsigned long long v = s_wk[buf][j]; if (v > bk) bk = v; }
        if (t == 0)
            __hip_atomic_store(&slots[buf * G + g], bk, __ATOMIC_RELAXED,
                               __HIP_MEMORY_SCOPE_AGENT);

        // ALL waves poll the 16 block slots: lane i watches slot i&15 (one
        // coalesced 128B load per iteration), then reduce in-register.
        unsigned long long kk;
        unsigned long long* myslot = &slots[buf * G + (lane & 15)];
        do {
            kk = __hip_atomic_load(myslot, __ATOMIC_RELAXED, __HIP_MEMORY_SCOPE_AGENT);
        } while (__any((unsigned)(kk & 0x7FFull) != tag));

        #pragma unroll
        for (int off = 1; off < 16; off <<= 1) {
            unsigned long long o = (unsigned long long)__shfl_xor((long long)kk, off, 64);
            if (o > kk) kk = o;
        }
        int sel = 32767 - (int)((kk >> 17) & 0x7FFF);
        sel = __builtin_amdgcn_readfirstlane(sel);   // wave-uniform -> scalar path

        if (g == 0 && t == 0) {
            out_idx[(size_t)b * S + s] = (float)sel;
            idx_int[b * S + s] = sel;
        }
        c4 = p4[sel];      // uniform gather of next centroid
    }
}

// ---------------------------------------------------------------------------
// Ball query counts: one block (256 thr) per (batch, centroid).
// ---------------------------------------------------------------------------
__launch_bounds__(256)
__global__ void ballq_kernel(const float* __restrict__ ws,
                             const int* __restrict__ idx_int,
                             float* __restrict__ out_counts) {
    __shared__ int s_part[4];
    const int b = blockIdx.x >> 10;
    const int j = blockIdx.x & 1023;
    const int t = threadIdx.x;
    const float* __restrict__ px = ws + (size_t)b * N;
    const float* __restrict__ py = ws + (size_t)(B + b) * N;
    const float* __restrict__ pz = ws + (size_t)(2 * B + b) * N;

    const int ci = idx_int[b * S + j];
    const float cx = px[ci], cy = py[ci], cz = pz[ci];

    int cnt = 0;
    #pragma unroll 4
    for (int p = t; p < N; p += 256) {
        float dx = __fsub_rn(cx, px[p]);
        float dy = __fsub_rn(cy, py[p]);
        float dz = __fsub_rn(cz, pz[p]);
        float d2 = __fadd_rn(__fadd_rn(__fmul_rn(dx, dx), __fmul_rn(dy, dy)),
                             __fmul_rn(dz, dz));
        cnt += (d2 <= RAD2) ? 1 : 0;
    }
    #pragma unroll
    for (int off = 1; off < 64; off <<= 1)
        cnt += __shfl_xor(cnt, off, 64);
    if ((t & 63) == 0) s_part[t >> 6] = cnt;
    __syncthreads();
    if (t == 0)
        out_counts[b * S + j] = (float)(s_part[0] + s_part[1] + s_part[2] + s_part[3]);
}

// ---------------------------------------------------------------------------
extern "C" void kernel_launch(void* const* d_in, const int* in_sizes, int n_in,
                              void* d_out, int out_size, void* d_ws, size_t ws_size,
                              hipStream_t stream) {
    const float* x = (const float*)d_in[0];
    float* out = (float*)d_out;
    float* ws = (float*)d_ws;   // px|py|pz (3BN) | float4 pack (4BN) | idx ints | slots
    int* idx_int = (int*)(ws + (size_t)7 * B * N);
    unsigned long long* gslot = (unsigned long long*)(idx_int + B * S);  // 8B-aligned

    float* out_x      = out;                         // B*N*D floats
    float* out_idx    = out + (size_t)B * N * D;     // B*S floats (idx as f32)
    float* out_counts = out_idx + (size_t)B * S;     // B*S floats (counts as f32)

    // zero the B*2*G u64 sync slots every launch (deterministic, capturable)
    hipMemsetAsync(gslot, 0, (size_t)B * 2 * G * sizeof(unsigned long long), stream);

    hipLaunchKernelGGL(pack_kernel, dim3((B * N + 255) / 256), dim3(256), 0, stream, x, ws);
    hipLaunchKernelGGL(fps_copy_kernel, dim3(NFPS + COPY_BLOCKS), dim3(TPB), 0, stream,
                       x, ws, gslot, out_idx, idx_int, out_x);
    hipLaunchKernelGGL(ballq_kernel, dim3(B * S), dim3(256), 0, stream, ws, idx_int, out_counts);
}

// Round 9
// 1939.351 us; speedup vs baseline: 2.2401x; 1.2133x over previous
//
#include <hip/hip_runtime.h>
#include <math.h>

#define B 4
#define N 32768
#define D 131
#define S 1024
#define RAD2 0.1f      // reference compares d2 <= RADIUS (=0.1) on SQUARED distance
#define G 16           // FPS blocks per batch
#define TPB 256        // threads per fps/copy block
#define PPT 8          // points per thread
#define NFPS (B * G)   // 64 fps blocks
#define COPY_BLOCKS 192

// ---------------------------------------------------------------------------
// Pack pts = x[:,:,:3] into SoA (px|py|pz) AND packed float4 {x,y,z,0}.
// ---------------------------------------------------------------------------
__global__ void pack_kernel(const float* __restrict__ x, float* __restrict__ ws) {
    int i = blockIdx.x * blockDim.x + threadIdx.x;
    if (i < B * N) {
        const float* __restrict__ s = x + (size_t)i * D;
        float a = s[0], bb = s[1], c = s[2];
        ws[i]             = a;
        ws[B * N + i]     = bb;
        ws[2 * B * N + i] = c;
        float4* w4 = (float4*)(ws + (size_t)3 * B * N);
        w4[i] = make_float4(a, bb, c, 0.0f);
    }
}

// ---------------------------------------------------------------------------
// Fused FPS + copy. 256 blocks x 256 thr.
// FPS blocks [0,64): 16 blocks/batch, 8 pts/thread. Per step:
//   compute -> wave butterfly -> LDS wavekeys -> barrier -> blockkey ->
//   t0 stores slot (agent,relaxed,tagged) ->
//   WAVE0 ONLY: poll 16 slots (lane i -> slot i&15; 64 pollers chip-wide),
//     on success: prefetch per-lane candidate coords p4[idx] OVERLAPPED with
//     the 4-stage key reduce; ballot -> shfl winner coords; lane0 publishes
//     {cx,cy,cz} + monotone tag to LDS.
//   OTHER WAVES: spin on LDS tag (no L3 traffic), fence, read coords.
// Copy blocks [64,256): grid-stride float4 copy of x (fps uses ~0 HBM BW).
// Key: [f32 val:32][32767-idx:15][0:6][tag=s+1:11]; equal tags => u64 max =
// (max val, then min idx) = exact ref tie-break.
// Slot double-buffer safety: overwrite of buf at s+2 happens only after the
// writer's s+1 poll succeeded; a completed load's value can't be clobbered.
// LDS bcast single-slot safety: tag s+2 written only after barrier(s+1),
// which all waves reach only after consuming bcast(s).
// ---------------------------------------------------------------------------
__launch_bounds__(TPB)
__global__ void fps_copy_kernel(const float* __restrict__ x,
                                const float* __restrict__ ws,
                                unsigned long long* __restrict__ gslot, // [B][2][G] zeroed
                                float* __restrict__ out_idx,
                                int* __restrict__ idx_int,
                                float* __restrict__ out_x) {
    if (blockIdx.x >= NFPS) {
        const size_t total4 = (size_t)B * N * D / 4;
        const float4* __restrict__ src = (const float4*)x;
        float4* __restrict__ dst = (float4*)out_x;
        for (size_t i = (size_t)(blockIdx.x - NFPS) * TPB + threadIdx.x; i < total4;
             i += (size_t)COPY_BLOCKS * TPB)
            dst[i] = src[i];
        return;
    }

    const int b = blockIdx.x >> 4;          // batch
    const int g = blockIdx.x & 15;          // participant id within batch
    const int t = threadIdx.x;
    const int lane = t & 63;
    const int w = t >> 6;                   // wave 0..3

    __shared__ unsigned long long s_wk[2][4];   // double-buffered wave keys
    __shared__ float s_bc[3];                   // broadcast centroid coords
    __shared__ unsigned s_tag;                  // monotone step tag

    const float* __restrict__ px = ws + (size_t)b * N;
    const float* __restrict__ py = ws + (size_t)(B + b) * N;
    const float* __restrict__ pz = ws + (size_t)(2 * B + b) * N;
    const float4* __restrict__ p4 = (const float4*)(ws + (size_t)3 * B * N) + (size_t)b * N;
    unsigned long long* __restrict__ slots = gslot + (size_t)b * 2 * G;

    const int base = g * (N / G);
    float lx[PPT], ly[PPT], lz[PPT], lcl[PPT];
    #pragma unroll
    for (int i = 0; i < PPT / 2; ++i) {
        int p = base + 2 * t + 2 * TPB * i;
        float2 vx = *(const float2*)&px[p];
        float2 vy = *(const float2*)&py[p];
        float2 vz = *(const float2*)&pz[p];
        lx[2*i] = vx.x; lx[2*i+1] = vx.y;
        ly[2*i] = vy.x; ly[2*i+1] = vy.y;
        lz[2*i] = vz.x; lz[2*i+1] = vz.y;
        lcl[2*i] = INFINITY; lcl[2*i+1] = INFINITY;
    }
    if (t == 0) s_tag = 0;          // LDS is not zero-initialized
    __syncthreads();

    float4 cq = p4[0];
    float cx = cq.x, cy = cq.y, cz = cq.z;   // centroid 0 (ref starts at sel=0)

    for (int s = 0; s < S; ++s) {
        float best = -INFINITY;
        int   bidx = 0;
        #pragma unroll
        for (int i = 0; i < PPT / 2; ++i) {
            const int p = base + 2 * t + 2 * TPB * i;
            {
                float dx = __fsub_rn(cx, lx[2*i]);
                float dy = __fsub_rn(cy, ly[2*i]);
                float dz = __fsub_rn(cz, lz[2*i]);
                float d2 = __fadd_rn(__fadd_rn(__fmul_rn(dx, dx), __fmul_rn(dy, dy)),
                                     __fmul_rn(dz, dz));
                float c = fminf(lcl[2*i], d2);
                lcl[2*i] = c;
                if (c > best) { best = c; bidx = p; }     // strict >: smallest p wins
            }
            {
                float dx = __fsub_rn(cx, lx[2*i+1]);
                float dy = __fsub_rn(cy, ly[2*i+1]);
                float dz = __fsub_rn(cz, lz[2*i+1]);
                float d2 = __fadd_rn(__fadd_rn(__fmul_rn(dx, dx), __fmul_rn(dy, dy)),
                                     __fmul_rn(dz, dz));
                float c = fminf(lcl[2*i+1], d2);
                lcl[2*i+1] = c;
                if (c > best) { best = c; bidx = p + 1; }
            }
        }

        // intra-wave butterfly argmax on (value, smallest idx)
        unsigned hi  = __float_as_uint(best);
        unsigned lo2 = (unsigned)(32767 - bidx);
        #define FPS_COMBINE(OHI, OLO) \
            { unsigned _oh = (OHI), _ol = (OLO); \
              if (_oh > hi || (_oh == hi && _ol > lo2)) { hi = _oh; lo2 = _ol; } }
        { unsigned a = (unsigned)__builtin_amdgcn_update_dpp(0, (int)hi, 0xB1, 0xf, 0xf, true);
          unsigned c2 = (unsigned)__builtin_amdgcn_update_dpp(0, (int)lo2, 0xB1, 0xf, 0xf, true);
          FPS_COMBINE(a, c2); }
        { unsigned a = (unsigned)__builtin_amdgcn_update_dpp(0, (int)hi, 0x4E, 0xf, 0xf, true);
          unsigned c2 = (unsigned)__builtin_amdgcn_update_dpp(0, (int)lo2, 0x4E, 0xf, 0xf, true);
          FPS_COMBINE(a, c2); }
        { unsigned a = (unsigned)__builtin_amdgcn_update_dpp(0, (int)hi, 0x141, 0xf, 0xf, true);
          unsigned c2 = (unsigned)__builtin_amdgcn_update_dpp(0, (int)lo2, 0x141, 0xf, 0xf, true);
          FPS_COMBINE(a, c2); }
        { unsigned a = (unsigned)__builtin_amdgcn_update_dpp(0, (int)hi, 0x140, 0xf, 0xf, true);
          unsigned c2 = (unsigned)__builtin_amdgcn_update_dpp(0, (int)lo2, 0x140, 0xf, 0xf, true);
          FPS_COMBINE(a, c2); }
        { unsigned a = (unsigned)__builtin_amdgcn_ds_swizzle((int)hi, 0x401F);
          unsigned c2 = (unsigned)__builtin_amdgcn_ds_swizzle((int)lo2, 0x401F);
          FPS_COMBINE(a, c2); }
        { unsigned a = (unsigned)__shfl_xor((int)hi, 32, 64);
          unsigned c2 = (unsigned)__shfl_xor((int)lo2, 32, 64);
          FPS_COMBINE(a, c2); }
        #undef FPS_COMBINE

        const int buf = s & 1;
        const unsigned tag = (unsigned)(s + 1);
        const unsigned long long mykey = ((unsigned long long)hi << 32) |
                                         ((unsigned long long)lo2 << 17) | tag;
        if (lane == 0) s_wk[buf][w] = mykey;
        __syncthreads();                             // the ONLY barrier per step

        if (w == 0) {
            // block key = max of 4 wave keys
            unsigned long long bk = s_wk[buf][0];
            #pragma unroll
            for (int j = 1; j < 4; ++j) { unsigned long long v = s_wk[buf][j]; if (v > bk) bk = v; }
            if (lane == 0)
                __hip_atomic_store(&slots[buf * G + g], bk, __ATOMIC_RELAXED,
                                   __HIP_MEMORY_SCOPE_AGENT);

            // poll 16 slots: lane i watches slot i&15 (one coalesced load/iter)
            unsigned long long kk;
            unsigned long long* myslot = &slots[buf * G + (lane & 15)];
            do {
                kk = __hip_atomic_load(myslot, __ATOMIC_RELAXED, __HIP_MEMORY_SCOPE_AGENT);
            } while (__any((unsigned)(kk & 0x7FFull) != tag));

            // prefetch per-lane candidate coords, OVERLAPPED with key reduce
            const unsigned long long kko = kk;
            const int idxc = 32767 - (int)((kko >> 17) & 0x7FFF);
            const float4 cand = p4[idxc];            // issued before the reduce

            #pragma unroll
            for (int off = 1; off < 16; off <<= 1) {
                unsigned long long o = (unsigned long long)__shfl_xor((long long)kk, off, 64);
                if (o > kk) kk = o;
            }
            // winning lane's prefetched coords
            unsigned long long mask = __ballot(kko == kk);
            int src = (int)(__ffsll((unsigned long long)mask) - 1);
            cx = __shfl(cand.x, src, 64);
            cy = __shfl(cand.y, src, 64);
            cz = __shfl(cand.z, src, 64);

            if (lane == 0) {
                s_bc[0] = cx; s_bc[1] = cy; s_bc[2] = cz;
                __threadfence_block();               // coords visible before tag
                __hip_atomic_store(&s_tag, tag, __ATOMIC_RELAXED,
                                   __HIP_MEMORY_SCOPE_WORKGROUP);
                if (g == 0) {
                    int sel = 32767 - (int)((kk >> 17) & 0x7FFF);
                    out_idx[(size_t)b * S + s] = (float)sel;
                    idx_int[b * S + s] = sel;
                }
            }
        } else {
            // spin on the local LDS tag (no global traffic), then read coords
            while (__hip_atomic_load(&s_tag, __ATOMIC_RELAXED,
                                     __HIP_MEMORY_SCOPE_WORKGROUP) != tag) {}
            __threadfence_block();
            cx = s_bc[0]; cy = s_bc[1]; cz = s_bc[2];
        }
    }
}

// ---------------------------------------------------------------------------
// Ball query counts: one block (256 thr) per (batch, centroid).
// ---------------------------------------------------------------------------
__launch_bounds__(256)
__global__ void ballq_kernel(const float* __restrict__ ws,
                             const int* __restrict__ idx_int,
                             float* __restrict__ out_counts) {
    __shared__ int s_part[4];
    const int b = blockIdx.x >> 10;
    const int j = blockIdx.x & 1023;
    const int t = threadIdx.x;
    const float* __restrict__ px = ws + (size_t)b * N;
    const float* __restrict__ py = ws + (size_t)(B + b) * N;
    const float* __restrict__ pz = ws + (size_t)(2 * B + b) * N;

    const int ci = idx_int[b * S + j];
    const float cx = px[ci], cy = py[ci], cz = pz[ci];

    int cnt = 0;
    #pragma unroll 4
    for (int p = t; p < N; p += 256) {
        float dx = __fsub_rn(cx, px[p]);
        float dy = __fsub_rn(cy, py[p]);
        float dz = __fsub_rn(cz, pz[p]);
        float d2 = __fadd_rn(__fadd_rn(__fmul_rn(dx, dx), __fmul_rn(dy, dy)),
                             __fmul_rn(dz, dz));
        cnt += (d2 <= RAD2) ? 1 : 0;
    }
    #pragma unroll
    for (int off = 1; off < 64; off <<= 1)
        cnt += __shfl_xor(cnt, off, 64);
    if ((t & 63) == 0) s_part[t >> 6] = cnt;
    __syncthreads();
    if (t == 0)
        out_counts[b * S + j] = (float)(s_part[0] + s_part[1] + s_part[2] + s_part[3]);
}

// ---------------------------------------------------------------------------
extern "C" void kernel_launch(void* const* d_in, const int* in_sizes, int n_in,
                              void* d_out, int out_size, void* d_ws, size_t ws_size,
                              hipStream_t stream) {
    const float* x = (const float*)d_in[0];
    float* out = (float*)d_out;
    float* ws = (float*)d_ws;   // px|py|pz (3BN) | float4 pack (4BN) | idx ints | slots
    int* idx_int = (int*)(ws + (size_t)7 * B * N);
    unsigned long long* gslot = (unsigned long long*)(idx_int + B * S);

    float* out_x      = out;                         // B*N*D floats
    float* out_idx    = out + (size_t)B * N * D;     // B*S floats (idx as f32)
    float* out_counts = out_idx + (size_t)B * S;     // B*S floats (counts as f32)

    hipMemsetAsync(gslot, 0, (size_t)B * 2 * G * sizeof(unsigned long long), stream);

    hipLaunchKernelGGL(pack_kernel, dim3((B * N + 255) / 256), dim3(256), 0, stream, x, ws);
    hipLaunchKernelGGL(fps_copy_kernel, dim3(NFPS + COPY_BLOCKS), dim3(TPB), 0, stream,
                       x, ws, gslot, out_idx, idx_int, out_x);
    hipLaunchKernelGGL(ballq_kernel, dim3(B * S), dim3(256), 0, stream, ws, idx_int, out_counts);
}